// Round 1
// baseline (2737.888 us; speedup 1.0000x reference)
//
#include <hip/hip_runtime.h>

#define NATOMS 10000
constexpr float SF_ = 0.17677669529663687f;   // 1/sqrt(32)
constexpr float C3_ = 0.57735026918962576f;   // 1/sqrt(3)
constexpr float C6_ = 0.40824829046386302f;   // 1/sqrt(6)

__device__ __forceinline__ float silu_(float x) { return x / (1.f + __expf(-x)); }

// ---------------------------------------------------------------------------
// K1: proj = edge_embedding @ proj_W  [E,64]@[64,192]
//     cols 0:128 -> out[:,0:128];  cols 128:192 -> env_weight -> atomic scatter env0
// ---------------------------------------------------------------------------
__global__ __launch_bounds__(256, 2) void k_proj(
    const float* __restrict__ X, const float* __restrict__ W,
    const int* __restrict__ center, const float* __restrict__ basis,
    float* __restrict__ out, float* __restrict__ env0, int E)
{
    __shared__ float Ws[64 * 192];
    __shared__ float Xs[64 * 64];
    __shared__ float bas_s[64 * 4];
    __shared__ int   ctr_s[64];
    const int t = threadIdx.x;
    const long e0 = (long)blockIdx.x * 64;

#pragma unroll
    for (int i = 0; i < 12; ++i) {
        int idx = (t + i * 256) * 4;
        *(float4*)&Ws[idx] = *(const float4*)&W[idx];
    }
#pragma unroll
    for (int i = 0; i < 4; ++i) {
        int idx = t + i * 256;            // 1024 float4
        int le = idx >> 4, kq = idx & 15;
        *(float4*)&Xs[le * 64 + kq * 4] = *(const float4*)&X[(e0 + le) * 64 + kq * 4];
    }
    if (t < 64) {
        ctr_s[t] = center[e0 + t];
        *(float4*)&bas_s[t * 4] = *(const float4*)&basis[(e0 + t) * 4];
    }
    __syncthreads();

    const int c = t & 31, eg = t >> 5;
    float acc[8][6];
#pragma unroll
    for (int i = 0; i < 8; ++i)
#pragma unroll
        for (int j = 0; j < 6; ++j) acc[i][j] = 0.f;

#pragma unroll 4
    for (int k = 0; k < 64; ++k) {
        const float* wr = &Ws[k * 192 + c];
        float w0 = wr[0], w1 = wr[32], w2 = wr[64], w3 = wr[96], w4 = wr[128], w5 = wr[160];
#pragma unroll
        for (int i = 0; i < 8; ++i) {
            float xk = Xs[(eg * 8 + i) * 64 + k];
            acc[i][0] += xk * w0; acc[i][1] += xk * w1; acc[i][2] += xk * w2;
            acc[i][3] += xk * w3; acc[i][4] += xk * w4; acc[i][5] += xk * w5;
        }
    }

#pragma unroll
    for (int i = 0; i < 8; ++i) {
        int le = eg * 8 + i;
        long e = e0 + le;
        float* orow = out + e * 384;
        orow[c]      = acc[i][0];
        orow[c + 32] = acc[i][1];
        orow[c + 64] = acc[i][2];
        orow[c + 96] = acc[i][3];
        int atom = ctr_s[le];
        float b0 = bas_s[le * 4 + 0], b1 = bas_s[le * 4 + 1];
        float b2 = bas_s[le * 4 + 2], b3 = bas_s[le * 4 + 3];
        float* eb = env0 + (long)atom * 128;
        {   // env_w index c  -> u = c>>1, comp = c&1
            int u = c >> 1;
            float wv = acc[i][4];
            if ((c & 1) == 0) atomicAdd(eb + u * 4 + 0, b0 * wv);
            else {
                atomicAdd(eb + u * 4 + 1, b1 * wv);
                atomicAdd(eb + u * 4 + 2, b2 * wv);
                atomicAdd(eb + u * 4 + 3, b3 * wv);
            }
        }
        {   // env_w index c+32 -> u = 16 + (c>>1)
            int u = (c >> 1) + 16;
            float wv = acc[i][5];
            if ((c & 1) == 0) atomicAdd(eb + u * 4 + 0, b0 * wv);
            else {
                atomicAdd(eb + u * 4 + 1, b1 * wv);
                atomicAdd(eb + u * 4 + 2, b2 * wv);
                atomicAdd(eb + u * 4 + 3, b3 * wv);
            }
        }
    }
}

// ---------------------------------------------------------------------------
// K2: contracter 1 (5 paths). tf_out [E,32,4] = [o0 | o1xyz]
// ---------------------------------------------------------------------------
__global__ __launch_bounds__(256, 2) void k_tp0(
    const float* __restrict__ tfeat, const float* __restrict__ env,
    const int* __restrict__ center,
    const float* __restrict__ w00, const float* __restrict__ w110,
    const float* __restrict__ w011, const float* __restrict__ w101,
    const float* __restrict__ w111,
    float* __restrict__ tfout, int E)
{
    __shared__ float t4[32 * 32 * 12];     // packed t values, 3 float4 per (e,u)
    __shared__ float Wm[5 * 1024];
    __shared__ int   ctr_s[32];
    const int t = threadIdx.x;
    const long e0 = (long)blockIdx.x * 32;

    ((float4*)&Wm[0])[t]    = ((const float4*)w00)[t];
    ((float4*)&Wm[1024])[t] = ((const float4*)w110)[t];
    ((float4*)&Wm[2048])[t] = ((const float4*)w011)[t];
    ((float4*)&Wm[3072])[t] = ((const float4*)w101)[t];
    ((float4*)&Wm[4096])[t] = ((const float4*)w111)[t];
    if (t < 32) ctr_s[t] = center[e0 + t];
    __syncthreads();

#pragma unroll
    for (int i = 0; i < 4; ++i) {
        int idx = t + i * 256;
        int le = idx >> 5, u = idx & 31;
        float4 a = *(const float4*)&tfeat[((e0 + le) * 32 + u) * 4];
        float4 b = *(const float4*)&env[((long)ctr_s[le] * 32 + u) * 4];
        float s1 = a.x, v1x = a.y, v1y = a.z, v1z = a.w;
        float s2 = b.x * SF_, v2x = b.y * SF_, v2y = b.z * SF_, v2z = b.w * SF_;
        float4 q0 = make_float4(s1 * s2, s1 * v2x * C3_, s1 * v2y * C3_, s1 * v2z * C3_);
        float4 q1 = make_float4((v1x * v2x + v1y * v2y + v1z * v2z) * C3_,
                                v1x * s2 * C3_, v1y * s2 * C3_, v1z * s2 * C3_);
        float4 q2 = make_float4((v1y * v2z - v1z * v2y) * C6_,
                                (v1z * v2x - v1x * v2z) * C6_,
                                (v1x * v2y - v1y * v2x) * C6_, 0.f);
        float* p = &t4[idx * 12];
        *(float4*)p = q0; *(float4*)(p + 4) = q1; *(float4*)(p + 8) = q2;
    }
    __syncthreads();

    const int v = t & 31, eg = t >> 5;
    float o0[4] = {0, 0, 0, 0};
    float o1[4][3] = {};
    for (int u = 0; u < 32; ++u) {
        float a00  = Wm[u * 32 + v];
        float a110 = Wm[1024 + u * 32 + v];
        float a011 = Wm[2048 + u * 32 + v];
        float a101 = Wm[3072 + u * 32 + v];
        float a111 = Wm[4096 + u * 32 + v];
#pragma unroll
        for (int i = 0; i < 4; ++i) {
            const float* p = &t4[((eg * 4 + i) * 32 + u) * 12];
            float4 q0 = *(const float4*)p;
            float4 q1 = *(const float4*)(p + 4);
            float4 q2 = *(const float4*)(p + 8);
            o0[i]    += a00 * q0.x + a110 * q1.x;
            o1[i][0] += a011 * q0.y + a101 * q1.y + a111 * q2.x;
            o1[i][1] += a011 * q0.z + a101 * q1.z + a111 * q2.y;
            o1[i][2] += a011 * q0.w + a101 * q1.z * 0.f + a101 * q1.w + a111 * q2.z;
        }
    }
#pragma unroll
    for (int i = 0; i < 4; ++i) {
        long e = e0 + eg * 4 + i;
        *(float4*)&tfout[(e * 32 + v) * 4] = make_float4(o0[i], o1[i][0], o1[i][1], o1[i][2]);
    }
}

// ---------------------------------------------------------------------------
// K3: mlp0: X=[proj128 | tf scalars] [E,160] -> silu(X@W1)@W2 [E,192]
//     cols 0:128 -> out[:,128:256]; cols 128:192 -> env scatter env1
// ---------------------------------------------------------------------------
__global__ __launch_bounds__(256, 2) void k_mlp0(
    const float* outr, const float* __restrict__ tfw,
    const float* __restrict__ W1, const float* __restrict__ W2,
    const int* __restrict__ center, const float* __restrict__ basis,
    float* outw, float* __restrict__ env1, int E)
{
    __shared__ float Xs[64 * 160];
    __shared__ float Hs[64 * 128];
    __shared__ float bas_s[64 * 4];
    __shared__ int   ctr_s[64];
    const int t = threadIdx.x;
    const long e0 = (long)blockIdx.x * 64;

#pragma unroll
    for (int i = 0; i < 8; ++i) {
        int idx = t + i * 256;           // 2048 float4 of proj cols
        int le = idx >> 5, q = idx & 31;
        *(float4*)&Xs[le * 160 + q * 4] = *(const float4*)&outr[(e0 + le) * 384 + q * 4];
    }
#pragma unroll
    for (int i = 0; i < 8; ++i) {
        int idx = t + i * 256;           // 2048 scalars (tf[:,:,0])
        int le = idx >> 5, u = idx & 31;
        Xs[le * 160 + 128 + u] = tfw[((e0 + le) * 32 + u) * 4];
    }
    if (t < 64) {
        ctr_s[t] = center[e0 + t];
        *(float4*)&bas_s[t * 4] = *(const float4*)&basis[(e0 + t) * 4];
    }
    __syncthreads();

    const int c = t & 31, eg = t >> 5;
    float h[8][4];
#pragma unroll
    for (int i = 0; i < 8; ++i)
#pragma unroll
        for (int j = 0; j < 4; ++j) h[i][j] = 0.f;

#pragma unroll 2
    for (int k = 0; k < 160; ++k) {
        const float* wr = &W1[k * 128 + c];
        float w0 = wr[0], w1 = wr[32], w2 = wr[64], w3 = wr[96];
#pragma unroll
        for (int i = 0; i < 8; ++i) {
            float xk = Xs[(eg * 8 + i) * 160 + k];
            h[i][0] += xk * w0; h[i][1] += xk * w1; h[i][2] += xk * w2; h[i][3] += xk * w3;
        }
    }
#pragma unroll
    for (int i = 0; i < 8; ++i) {
        int le = eg * 8 + i;
        Hs[le * 128 + c]      = silu_(h[i][0]);
        Hs[le * 128 + c + 32] = silu_(h[i][1]);
        Hs[le * 128 + c + 64] = silu_(h[i][2]);
        Hs[le * 128 + c + 96] = silu_(h[i][3]);
    }
    __syncthreads();

    float o[8][6];
#pragma unroll
    for (int i = 0; i < 8; ++i)
#pragma unroll
        for (int j = 0; j < 6; ++j) o[i][j] = 0.f;

#pragma unroll 2
    for (int k = 0; k < 128; ++k) {
        const float* wr = &W2[k * 192 + c];
        float w0 = wr[0], w1 = wr[32], w2 = wr[64], w3 = wr[96], w4 = wr[128], w5 = wr[160];
#pragma unroll
        for (int i = 0; i < 8; ++i) {
            float hk = Hs[(eg * 8 + i) * 128 + k];
            o[i][0] += hk * w0; o[i][1] += hk * w1; o[i][2] += hk * w2;
            o[i][3] += hk * w3; o[i][4] += hk * w4; o[i][5] += hk * w5;
        }
    }

#pragma unroll
    for (int i = 0; i < 8; ++i) {
        int le = eg * 8 + i;
        long e = e0 + le;
        float* orow = outw + e * 384 + 128;
        orow[c]      = o[i][0];
        orow[c + 32] = o[i][1];
        orow[c + 64] = o[i][2];
        orow[c + 96] = o[i][3];
        int atom = ctr_s[le];
        float b0 = bas_s[le * 4 + 0], b1 = bas_s[le * 4 + 1];
        float b2 = bas_s[le * 4 + 2], b3 = bas_s[le * 4 + 3];
        float* eb = env1 + (long)atom * 128;
        {
            int u = c >> 1;
            float wv = o[i][4];
            if ((c & 1) == 0) atomicAdd(eb + u * 4 + 0, b0 * wv);
            else {
                atomicAdd(eb + u * 4 + 1, b1 * wv);
                atomicAdd(eb + u * 4 + 2, b2 * wv);
                atomicAdd(eb + u * 4 + 3, b3 * wv);
            }
        }
        {
            int u = (c >> 1) + 16;
            float wv = o[i][5];
            if ((c & 1) == 0) atomicAdd(eb + u * 4 + 0, b0 * wv);
            else {
                atomicAdd(eb + u * 4 + 1, b1 * wv);
                atomicAdd(eb + u * 4 + 2, b2 * wv);
                atomicAdd(eb + u * 4 + 3, b3 * wv);
            }
        }
    }
}

// ---------------------------------------------------------------------------
// K4: contracter 2 (paths 000, 110 only) -> scalars2 [E,32]
// ---------------------------------------------------------------------------
__global__ __launch_bounds__(256, 2) void k_tp1(
    const float* __restrict__ tfw, const float* __restrict__ env,
    const int* __restrict__ center,
    const float* __restrict__ w00, const float* __restrict__ w110,
    float* __restrict__ scal2, int E)
{
    __shared__ float t2[32 * 32 * 2];
    __shared__ float Wm[2 * 1024];
    __shared__ int   ctr_s[32];
    const int t = threadIdx.x;
    const long e0 = (long)blockIdx.x * 32;
    ((float4*)&Wm[0])[t]    = ((const float4*)w00)[t];
    ((float4*)&Wm[1024])[t] = ((const float4*)w110)[t];
    if (t < 32) ctr_s[t] = center[e0 + t];
    __syncthreads();

#pragma unroll
    for (int i = 0; i < 4; ++i) {
        int idx = t + i * 256;
        int le = idx >> 5, u = idx & 31;
        float4 a = *(const float4*)&tfw[((e0 + le) * 32 + u) * 4];
        float4 b = *(const float4*)&env[((long)ctr_s[le] * 32 + u) * 4];
        float2 q;
        q.x = a.x * (b.x * SF_);
        q.y = (a.y * b.y + a.z * b.z + a.w * b.w) * (SF_ * C3_);
        *(float2*)&t2[idx * 2] = q;
    }
    __syncthreads();

    const int v = t & 31, eg = t >> 5;
    float acc[4] = {0, 0, 0, 0};
    for (int u = 0; u < 32; ++u) {
        float a0 = Wm[u * 32 + v], a1 = Wm[1024 + u * 32 + v];
#pragma unroll
        for (int i = 0; i < 4; ++i) {
            float2 q = *(const float2*)&t2[((eg * 4 + i) * 32 + u) * 2];
            acc[i] += a0 * q.x + a1 * q.y;
        }
    }
#pragma unroll
    for (int i = 0; i < 4; ++i)
        scal2[(e0 + eg * 4 + i) * 32 + v] = acc[i];
}

// ---------------------------------------------------------------------------
// K5: mlp1: X=[out cols 0:256 | scalars2] [E,288] -> silu(X@W1)@W2 [E,128]
//     -> out[:,256:384]
// ---------------------------------------------------------------------------
__global__ __launch_bounds__(256, 3) void k_mlp1(
    const float* outr, const float* __restrict__ scal2,
    const float* __restrict__ W1, const float* __restrict__ W2,
    float* outw, int E)
{
    __shared__ float Xs[32 * 288];
    __shared__ float Hs[32 * 128];
    const int t = threadIdx.x;
    const long e0 = (long)blockIdx.x * 32;

#pragma unroll
    for (int i = 0; i < 8; ++i) {
        int idx = t + i * 256;          // 2048 float4: 32 edges x 64 f4
        int le = idx >> 6, q = idx & 63;
        *(float4*)&Xs[le * 288 + q * 4] = *(const float4*)&outr[(e0 + le) * 384 + q * 4];
    }
    {
        int le = t >> 3, q = t & 7;
        *(float4*)&Xs[le * 288 + 256 + q * 4] = *(const float4*)&scal2[(e0 + le) * 32 + q * 4];
    }
    __syncthreads();

    const int c = t & 31, eg = t >> 5;
    float h[4][4];
#pragma unroll
    for (int i = 0; i < 4; ++i)
#pragma unroll
        for (int j = 0; j < 4; ++j) h[i][j] = 0.f;

#pragma unroll 2
    for (int k = 0; k < 288; ++k) {
        const float* wr = &W1[k * 128 + c];
        float w0 = wr[0], w1 = wr[32], w2 = wr[64], w3 = wr[96];
#pragma unroll
        for (int i = 0; i < 4; ++i) {
            float xk = Xs[(eg * 4 + i) * 288 + k];
            h[i][0] += xk * w0; h[i][1] += xk * w1; h[i][2] += xk * w2; h[i][3] += xk * w3;
        }
    }
#pragma unroll
    for (int i = 0; i < 4; ++i) {
        int le = eg * 4 + i;
        Hs[le * 128 + c]      = silu_(h[i][0]);
        Hs[le * 128 + c + 32] = silu_(h[i][1]);
        Hs[le * 128 + c + 64] = silu_(h[i][2]);
        Hs[le * 128 + c + 96] = silu_(h[i][3]);
    }
    __syncthreads();

    float o[4][4];
#pragma unroll
    for (int i = 0; i < 4; ++i)
#pragma unroll
        for (int j = 0; j < 4; ++j) o[i][j] = 0.f;

#pragma unroll 2
    for (int k = 0; k < 128; ++k) {
        const float* wr = &W2[k * 128 + c];
        float w0 = wr[0], w1 = wr[32], w2 = wr[64], w3 = wr[96];
#pragma unroll
        for (int i = 0; i < 4; ++i) {
            float hk = Hs[(eg * 4 + i) * 128 + k];
            o[i][0] += hk * w0; o[i][1] += hk * w1; o[i][2] += hk * w2; o[i][3] += hk * w3;
        }
    }
#pragma unroll
    for (int i = 0; i < 4; ++i) {
        long e = e0 + eg * 4 + i;
        float* orow = outw + e * 384 + 256;
        orow[c]      = o[i][0];
        orow[c + 32] = o[i][1];
        orow[c + 64] = o[i][2];
        orow[c + 96] = o[i][3];
    }
}

// ---------------------------------------------------------------------------
extern "C" void kernel_launch(void* const* d_in, const int* in_sizes, int n_in,
                              void* d_out, int out_size, void* d_ws, size_t ws_size,
                              hipStream_t stream)
{
    const int*   edge_index = (const int*)d_in[0];
    const float* basis  = (const float*)d_in[1];
    const float* tfeat  = (const float*)d_in[2];
    const float* eemb   = (const float*)d_in[3];
    const float* projW  = (const float*)d_in[5];
    const float* l0W1   = (const float*)d_in[6];
    const float* l0W2   = (const float*)d_in[7];
    const float* l1W1   = (const float*)d_in[8];
    const float* l1W2   = (const float*)d_in[9];
    const float* tp0w00  = (const float*)d_in[10];
    const float* tp0w110 = (const float*)d_in[11];
    const float* tp0w011 = (const float*)d_in[12];
    const float* tp0w101 = (const float*)d_in[13];
    const float* tp0w111 = (const float*)d_in[14];
    const float* tp1w00  = (const float*)d_in[15];
    const float* tp1w110 = (const float*)d_in[16];

    const int E = in_sizes[3] / 64;          // edge_embedding [E,64]
    const int* center = edge_index;          // row 0 of edge_index

    float* tfw   = (float*)d_ws;                    // [E,32,4]
    float* scal2 = tfw + (size_t)E * 128;           // [E,32]
    float* env0  = scal2 + (size_t)E * 32;          // [NATOMS,32,4]
    float* env1  = env0 + (size_t)NATOMS * 128;     // [NATOMS,32,4]
    float* out   = (float*)d_out;                   // [E,384]

    hipMemsetAsync(env0, 0, (size_t)2 * NATOMS * 128 * sizeof(float), stream);

    k_proj<<<E / 64, 256, 0, stream>>>(eemb, projW, center, basis, out, env0, E);
    k_tp0 <<<E / 32, 256, 0, stream>>>(tfeat, env0, center,
                                       tp0w00, tp0w110, tp0w011, tp0w101, tp0w111, tfw, E);
    k_mlp0<<<E / 64, 256, 0, stream>>>(out, tfw, l0W1, l0W2, center, basis, out, env1, E);
    k_tp1 <<<E / 32, 256, 0, stream>>>(tfw, env1, center, tp1w00, tp1w110, scal2, E);
    k_mlp1<<<E / 32, 256, 0, stream>>>(out, scal2, l1W1, l1W2, out, E);
}